// Round 8
// baseline (179.732 us; speedup 1.0000x reference)
//
#include <hip/hip_runtime.h>
#include <hip/hip_bf16.h>
#include <stdint.h>

#define B_   2
#define S_   2048
#define HID_ 1024
#define NH_  16
#define HD_  64

typedef __attribute__((ext_vector_type(4))) float f32x4;
typedef __attribute__((ext_vector_type(8))) short bf16x8;

__device__ inline unsigned short f2bf(float x) {
    __hip_bfloat16 h = __float2bfloat16(x);
    return reinterpret_cast<unsigned short&>(h);
}

__device__ inline void gload_lds16(const void* g, void* l) {
    __builtin_amdgcn_global_load_lds(
        (const __attribute__((address_space(1))) void*)g,
        (__attribute__((address_space(3))) void*)l, 16, 0, 0);
}

// ---------------------------------------------------------------------------
// Pass 0: fp32 -> bf16 conversion of X1, X2, Wq, Wk, Wv (unchanged).
// ---------------------------------------------------------------------------
__global__ __launch_bounds__(256) void cvt_all(
    const float* __restrict__ X1, const float* __restrict__ X2,
    const float* __restrict__ Wq, const float* __restrict__ Wk, const float* __restrict__ Wv,
    unsigned short* __restrict__ X1b, unsigned short* __restrict__ X2b,
    unsigned short* __restrict__ Wqb, unsigned short* __restrict__ Wkb,
    unsigned short* __restrict__ Wvb)
{
    const int id = blockIdx.x;
    const float* src;
    unsigned short* dst;
    int base;
    if (id < 2048)      { src = X1; dst = X1b; base = id; }
    else if (id < 4096) { src = X2; dst = X2b; base = id - 2048; }
    else if (id < 4608) { src = Wq; dst = Wqb; base = id - 4096; }
    else if (id < 5120) { src = Wk; dst = Wkb; base = id - 4608; }
    else                { src = Wv; dst = Wvb; base = id - 5120; }
    const size_t off = (size_t)base * 2048 + (size_t)threadIdx.x * 8;
    float4 a = *(const float4*)&src[off];
    float4 b = *(const float4*)&src[off + 4];
    unsigned short o[8] = {f2bf(a.x), f2bf(a.y), f2bf(a.z), f2bf(a.w),
                           f2bf(b.x), f2bf(b.y), f2bf(b.z), f2bf(b.w)};
    *(uint4*)&dst[off] = *(uint4*)o;
}

// ---------------------------------------------------------------------------
// QKV projection, m97 structure (unchanged from round 7).
// ---------------------------------------------------------------------------
__global__ __launch_bounds__(256, 3) void qkv_gemm(
    const unsigned short* __restrict__ X1b, const unsigned short* __restrict__ X2b,
    const unsigned short* __restrict__ Wqb, const unsigned short* __restrict__ Wkb,
    const unsigned short* __restrict__ Wvb,
    const float* __restrict__ bq, const float* __restrict__ bk, const float* __restrict__ bv,
    unsigned short* __restrict__ Qo, unsigned short* __restrict__ Ko, unsigned short* __restrict__ Vo)
{
    const int z = blockIdx.z;
    const unsigned short* X = (z == 0) ? X1b : X2b;
    const unsigned short* W = (z == 0) ? Wqb : (z == 1 ? Wkb : Wvb);
    const float* bias = (z == 0) ? bq : (z == 1 ? bk : bv);
    unsigned short* out = (z == 0) ? Qo : (z == 1 ? Ko : Vo);

    __shared__ __align__(16) unsigned short SM[128 * 132];
    unsigned short* As = SM;
    unsigned short* Bs = SM + 128 * 64;

    const int m0 = blockIdx.x * 128;
    const int n0 = blockIdx.y * 128;
    const int t = threadIdx.x;
    const int lane = t & 63;
    const int w = t >> 6;
    const int lo = lane & 15, hi = lane >> 4;
    const int wm = w >> 1, wn = w & 1;

    const int srow = lane >> 3;
    const int scol = (lane & 7) * 8;

    f32x4 acc[4][4];
    const f32x4 fzero = {0.f, 0.f, 0.f, 0.f};
    #pragma unroll
    for (int i = 0; i < 4; ++i)
        #pragma unroll
        for (int j = 0; j < 4; ++j) acc[i][j] = fzero;

    for (int kt = 0; kt < 16; ++kt) {
        __syncthreads();
        #pragma unroll
        for (int i = 0; i < 4; ++i) {
            const int r = w * 32 + i * 8 + srow;
            gload_lds16(&X[(size_t)(m0 + r) * HID_ + kt * 64 + scol],
                        &As[w * 2048 + i * 512]);
            gload_lds16(&W[(size_t)(n0 + r) * HID_ + kt * 64 + scol],
                        &Bs[w * 2048 + i * 512]);
        }
        __syncthreads();

        #pragma unroll
        for (int s = 0; s < 2; ++s) {
            bf16x8 a[4], b[4];
            #pragma unroll
            for (int i = 0; i < 4; ++i) {
                a[i] = *(const bf16x8*)&As[(wm * 64 + i * 16 + lo) * 64 + s * 32 + hi * 8];
                b[i] = *(const bf16x8*)&Bs[(wn * 64 + i * 16 + lo) * 64 + s * 32 + hi * 8];
            }
            #pragma unroll
            for (int i = 0; i < 4; ++i)
                #pragma unroll
                for (int j = 0; j < 4; ++j)
                    acc[i][j] = __builtin_amdgcn_mfma_f32_16x16x32_bf16(a[i], b[j], acc[i][j], 0, 0, 0);
        }
    }

    if (z != 2) {
        const float sc = (z == 0) ? 0.18033688011112042f : 1.0f;
        #pragma unroll
        for (int i = 0; i < 4; ++i) {
            #pragma unroll
            for (int j = 0; j < 4; ++j) {
                int col = n0 + wn * 64 + j * 16 + lo;
                float bb = bias[col];
                #pragma unroll
                for (int r = 0; r < 4; ++r) {
                    int row = m0 + wm * 64 + i * 16 + hi * 4 + r;
                    out[(size_t)row * HID_ + col] = f2bf((acc[i][j][r] + bb) * sc);
                }
            }
        }
    } else {
        __syncthreads();
        unsigned short* Ts = SM;
        #pragma unroll
        for (int i = 0; i < 4; ++i) {
            #pragma unroll
            for (int j = 0; j < 4; ++j) {
                int nl = wn * 64 + j * 16 + lo;
                float bb = bias[n0 + nl];
                int ml = wm * 64 + i * 16 + hi * 4;
                ushort4 pk;
                pk.x = f2bf(acc[i][j][0] + bb);
                pk.y = f2bf(acc[i][j][1] + bb);
                pk.z = f2bf(acc[i][j][2] + bb);
                pk.w = f2bf(acc[i][j][3] + bb);
                *(ushort4*)&Ts[nl * 132 + ml] = pk;
            }
        }
        __syncthreads();
        const int nn = t >> 1;
        const int mh = (t & 1) * 64;
        const int bI = m0 >> 11;
        const int sb = (m0 & 2047) + mh;
        size_t obase = (size_t)bI * ((size_t)HID_ * S_) + (size_t)(n0 + nn) * S_ + sb;
        #pragma unroll
        for (int kk = 0; kk < 8; ++kk)
            *(uint4*)&out[obase + kk * 8] = *(const uint4*)&Ts[nn * 132 + mh + kk * 8];
    }
}

// ---------------------------------------------------------------------------
// Flash attention with T15 rotation: QK(t+1) is computed right after the
// staging barrier, register-independent of softmax(t)+PV(t), so the MFMA
// pipe is fed during the softmax VALU phase. Two named score arrays sA/sB
// (static indexing), 2 barriers/tile, global loads issued 2 tiles ahead.
// Swapped-QK, static max (M=0), deferred l, in-register P via cvt_pk +
// permlane. 4 waves x 32 q = 128 q/block, KVBLK=128, double-buffered K/V.
// ---------------------------------------------------------------------------
__global__ __launch_bounds__(256, 2) void attn_fwd(
    const unsigned short* __restrict__ Q, const unsigned short* __restrict__ K,
    const unsigned short* __restrict__ Vt, float* __restrict__ out)
{
    __shared__ __align__(16) unsigned short Ks[2][128 * 72];   // [k][d]
    __shared__ __align__(16) unsigned short Vs[2][64 * 136];   // [d][k]

    const int t = threadIdx.x;
    const int lane = t & 63;
    const int w = t >> 6;
    const int lo = lane & 15, hi = lane >> 4;

    const int id = blockIdx.x + 16 * blockIdx.y;
    const int vb = (id & 7) * 64 + (id >> 3);
    const int qt = vb & 15;
    const int bh = vb >> 4;
    const int b = bh >> 4, h = bh & 15;

    const int q0 = qt * 128;
    const size_t baseQK = (size_t)b * S_ * HID_ + (size_t)h * HD_;
    const size_t baseV  = (size_t)b * ((size_t)HID_ * S_) + (size_t)h * ((size_t)HD_ * S_);

    bf16x8 qb[2][2];
    #pragma unroll
    for (int qf = 0; qf < 2; ++qf)
        #pragma unroll
        for (int st = 0; st < 2; ++st)
            qb[qf][st] = *(const bf16x8*)&Q[baseQK + (size_t)(q0 + w * 32 + qf * 16 + lo) * HID_ + st * 32 + hi * 8];

    f32x4 O[2][4];
    const f32x4 fzero = {0.f, 0.f, 0.f, 0.f};
    f32x4 lsv[2] = {fzero, fzero};
    #pragma unroll
    for (int qf = 0; qf < 2; ++qf)
        #pragma unroll
        for (int c = 0; c < 4; ++c) O[qf][c] = fzero;

    const int krow = t >> 1, kcb = (t & 1) * 32;
    const int vrow = t >> 2, vcb = (t & 3) * 32;

    uint4 kr[4], vr[4];

    auto GLOAD = [&](int tile) {
        const int kn = tile * 128;
        #pragma unroll
        for (int j = 0; j < 4; ++j) {
            kr[j] = *(const uint4*)&K[baseQK + (size_t)(kn + krow) * HID_ + kcb + 8 * j];
            vr[j] = *(const uint4*)&Vt[baseV + (size_t)vrow * S_ + kn + vcb + 8 * j];
        }
    };
    auto DSW = [&](int buf) {
        #pragma unroll
        for (int j = 0; j < 4; ++j) {
            *(uint4*)&Ks[buf][krow * 72 + kcb + 8 * j] = kr[j];
            *(uint4*)&Vs[buf][vrow * 136 + vcb + 8 * j] = vr[j];
        }
    };
    auto QK = [&](int buf, f32x4 (&s)[2][8]) {
        __builtin_amdgcn_s_setprio(1);
        #pragma unroll
        for (int n = 0; n < 8; ++n) {
            bf16x8 ka0 = *(const bf16x8*)&Ks[buf][(n * 16 + lo) * 72 + hi * 8];
            bf16x8 ka1 = *(const bf16x8*)&Ks[buf][(n * 16 + lo) * 72 + 32 + hi * 8];
            #pragma unroll
            for (int qf = 0; qf < 2; ++qf) {
                f32x4 z = fzero;
                z = __builtin_amdgcn_mfma_f32_16x16x32_bf16(ka0, qb[qf][0], z, 0, 0, 0);
                s[qf][n] = __builtin_amdgcn_mfma_f32_16x16x32_bf16(ka1, qb[qf][1], z, 0, 0, 0);
            }
        }
        __builtin_amdgcn_s_setprio(0);
    };
    // softmax (static max) + per-st pack + PV; pw live range = 8 regs
    auto SMPV = [&](f32x4 (&s)[2][8], int buf) {
        #pragma unroll
        for (int qf = 0; qf < 2; ++qf)
            #pragma unroll
            for (int n = 0; n < 8; ++n) {
                #pragma unroll
                for (int r = 0; r < 4; ++r) s[qf][n][r] = exp2f(s[qf][n][r]);
                lsv[qf] += s[qf][n];
            }
        #pragma unroll
        for (int st = 0; st < 4; ++st) {
            unsigned paw[2][4];
            #pragma unroll
            for (int qf = 0; qf < 2; ++qf) {
                #pragma unroll
                for (int p = 0; p < 2; ++p) {
                    unsigned X, Y;
                    asm("v_cvt_pk_bf16_f32 %0, %1, %2"
                        : "=v"(X) : "v"(s[qf][2 * st][2 * p]), "v"(s[qf][2 * st][2 * p + 1]));
                    asm("v_cvt_pk_bf16_f32 %0, %1, %2"
                        : "=v"(Y) : "v"(s[qf][2 * st + 1][2 * p]), "v"(s[qf][2 * st + 1][2 * p + 1]));
                    asm volatile("v_permlane32_swap_b32 %0, %1" : "+v"(X), "+v"(Y));
                    asm volatile("v_permlane16_swap_b32 %0, %1" : "+v"(X), "+v"(Y));
                    paw[qf][p] = X;
                    paw[qf][p + 2] = Y;
                }
            }
            bf16x8 pa0, pa1;
            #pragma unroll
            for (int j = 0; j < 4; ++j) {
                ((unsigned*)&pa0)[j] = paw[0][j];
                ((unsigned*)&pa1)[j] = paw[1][j];
            }
            __builtin_amdgcn_s_setprio(1);
            #pragma unroll
            for (int c = 0; c < 4; ++c) {
                bf16x8 vbf = *(const bf16x8*)&Vs[buf][(c * 16 + lo) * 136 + st * 32 + hi * 8];
                O[0][c] = __builtin_amdgcn_mfma_f32_16x16x32_bf16(pa0, vbf, O[0][c], 0, 0, 0);
                O[1][c] = __builtin_amdgcn_mfma_f32_16x16x32_bf16(pa1, vbf, O[1][c], 0, 0, 0);
            }
            __builtin_amdgcn_s_setprio(0);
        }
    };

    f32x4 sA[2][8], sB[2][8];

    // prologue: tile 0 staged + scored
    GLOAD(0);
    DSW(0);
    __syncthreads();
    GLOAD(1);
    QK(0, sA);

    for (int tt = 0; tt < 16; tt += 2) {
        // even body: consume sA (tile tt, buf0); produce sB (tile tt+1, buf1)
        DSW(1);                       // tile tt+1 (prev buf1 reads barriered)
        __syncthreads();
        if (tt + 2 < 16) GLOAD(tt + 2);
        QK(1, sB);                    // MFMA, independent of sA softmax
        SMPV(sA, 0);                  // VALU + PV interleaves with QK above
        __syncthreads();              // protect buf0 rewrite below

        if (tt + 2 < 16) {
            // odd body: consume sB (tile tt+1, buf1); produce sA (tile tt+2, buf0)
            DSW(0);                   // tile tt+2
            __syncthreads();
            if (tt + 3 < 16) GLOAD(tt + 3);
            QK(0, sA);
            SMPV(sB, 1);
            __syncthreads();
        } else {
            SMPV(sB, 1);              // tail: tile 15
        }
    }

    // epilogue: finish l, normalize, store fp32
    #pragma unroll
    for (int qf = 0; qf < 2; ++qf) {
        float l = lsv[qf][0] + lsv[qf][1] + lsv[qf][2] + lsv[qf][3];
        l += __shfl_xor(l, 16);
        l += __shfl_xor(l, 32);
        float linv[4];
        #pragma unroll
        for (int r = 0; r < 4; ++r)
            linv[r] = 1.0f / __shfl(l, (lane & 48) + hi * 4 + r);
        #pragma unroll
        for (int c = 0; c < 4; ++c) {
            #pragma unroll
            for (int r = 0; r < 4; ++r) {
                int q = q0 + w * 32 + qf * 16 + hi * 4 + r;
                out[(size_t)b * S_ * HID_ + (size_t)q * HID_ + h * HD_ + c * 16 + lo] =
                    O[qf][c][r] * linv[r];
            }
        }
    }
}

extern "C" void kernel_launch(void* const* d_in, const int* in_sizes, int n_in,
                              void* d_out, int out_size, void* d_ws, size_t ws_size,
                              hipStream_t stream) {
    const float* hs1 = (const float*)d_in[0];
    const float* hs2 = (const float*)d_in[1];
    const float* Wq  = (const float*)d_in[2];
    const float* bq  = (const float*)d_in[3];
    const float* Wk  = (const float*)d_in[4];
    const float* bk  = (const float*)d_in[5];
    const float* Wv  = (const float*)d_in[6];
    const float* bv  = (const float*)d_in[7];
    float* out = (float*)d_out;

    const size_t XY = (size_t)B_ * S_ * HID_;   // 4194304
    const size_t WW = (size_t)HID_ * HID_;      // 1048576
    unsigned short* Qb  = (unsigned short*)d_ws;
    unsigned short* Kb  = Qb + XY;
    unsigned short* Vb  = Kb + XY;              // V transposed [b][h*64+d][s]
    unsigned short* X1b = Vb + XY;
    unsigned short* X2b = X1b + XY;
    unsigned short* Wqb = X2b + XY;
    unsigned short* Wkb = Wqb + WW;
    unsigned short* Wvb = Wkb + WW;

    cvt_all<<<5632, 256, 0, stream>>>(hs1, hs2, Wq, Wk, Wv, X1b, X2b, Wqb, Wkb, Wvb);
    qkv_gemm<<<dim3(32, 8, 3), 256, 0, stream>>>(X1b, X2b, Wqb, Wkb, Wvb,
                                                 bq, bk, bv, Qb, Kb, Vb);
    attn_fwd<<<dim3(16, 32), 256, 0, stream>>>(Qb, Kb, Vb, out);
}

// Round 9
// 115.781 us; speedup vs baseline: 1.5523x; 1.5523x over previous
//
#include <hip/hip_runtime.h>
#include <hip/hip_bf16.h>
#include <stdint.h>

#define B_   2
#define S_   2048
#define HID_ 1024
#define NH_  16
#define HD_  64

typedef __attribute__((ext_vector_type(4))) float f32x4;
typedef __attribute__((ext_vector_type(8))) short bf16x8;

__device__ inline unsigned short f2bf(float x) {
    __hip_bfloat16 h = __float2bfloat16(x);
    return reinterpret_cast<unsigned short&>(h);
}

__device__ inline void gload_lds16(const void* g, void* l) {
    __builtin_amdgcn_global_load_lds(
        (const __attribute__((address_space(1))) void*)g,
        (__attribute__((address_space(3))) void*)l, 16, 0, 0);
}

// ---------------------------------------------------------------------------
// Pass 0: fp32 -> bf16 conversion of X1, X2, Wq, Wk, Wv (unchanged).
// ---------------------------------------------------------------------------
__global__ __launch_bounds__(256) void cvt_all(
    const float* __restrict__ X1, const float* __restrict__ X2,
    const float* __restrict__ Wq, const float* __restrict__ Wk, const float* __restrict__ Wv,
    unsigned short* __restrict__ X1b, unsigned short* __restrict__ X2b,
    unsigned short* __restrict__ Wqb, unsigned short* __restrict__ Wkb,
    unsigned short* __restrict__ Wvb)
{
    const int id = blockIdx.x;
    const float* src;
    unsigned short* dst;
    int base;
    if (id < 2048)      { src = X1; dst = X1b; base = id; }
    else if (id < 4096) { src = X2; dst = X2b; base = id - 2048; }
    else if (id < 4608) { src = Wq; dst = Wqb; base = id - 4096; }
    else if (id < 5120) { src = Wk; dst = Wkb; base = id - 4608; }
    else                { src = Wv; dst = Wvb; base = id - 5120; }
    const size_t off = (size_t)base * 2048 + (size_t)threadIdx.x * 8;
    float4 a = *(const float4*)&src[off];
    float4 b = *(const float4*)&src[off + 4];
    unsigned short o[8] = {f2bf(a.x), f2bf(a.y), f2bf(a.z), f2bf(a.w),
                           f2bf(b.x), f2bf(b.y), f2bf(b.z), f2bf(b.w)};
    *(uint4*)&dst[off] = *(uint4*)o;
}

// ---------------------------------------------------------------------------
// QKV projection, m97 structure, K+V MERGED:
// z==0: Q = X1 @ Wq^T (+bq), scaled by 0.125*log2(e)   -> [B*S][1024] bf16
// z==1: K = X2 @ Wk^T (+bk)                            -> [B*S][1024] bf16
//       V = X2 @ Wv^T (+bv), transposed                -> [b][h*64+d][s] bf16
// One X2 staging feeds both K and V (dual acc, dual B panel).
// ---------------------------------------------------------------------------
__global__ __launch_bounds__(256, 2) void qkv_gemm(
    const unsigned short* __restrict__ X1b, const unsigned short* __restrict__ X2b,
    const unsigned short* __restrict__ Wqb, const unsigned short* __restrict__ Wkb,
    const unsigned short* __restrict__ Wvb,
    const float* __restrict__ bq, const float* __restrict__ bk, const float* __restrict__ bv,
    unsigned short* __restrict__ Qo, unsigned short* __restrict__ Ko, unsigned short* __restrict__ Vo)
{
    const int z = blockIdx.z;
    const unsigned short* X  = (z == 0) ? X1b : X2b;
    const unsigned short* W0 = (z == 0) ? Wqb : Wkb;
    const unsigned short* W1 = Wvb;                    // only read when z==1

    // As | Bs0 | Bs1 : linear [128][64] bf16, 16 KB each (48 KB total).
    // V-transpose epilogue Ts[128][132] (33.8 KB) aliases the whole block.
    __shared__ __align__(16) unsigned short SM[3 * 128 * 64];
    unsigned short* As  = SM;
    unsigned short* Bs0 = SM + 128 * 64;
    unsigned short* Bs1 = SM + 2 * 128 * 64;

    const int m0 = blockIdx.x * 128;
    const int n0 = blockIdx.y * 128;
    const int t = threadIdx.x;
    const int lane = t & 63;
    const int w = t >> 6;
    const int lo = lane & 15, hi = lane >> 4;
    const int wm = w >> 1, wn = w & 1;

    const int srow = lane >> 3;           // 0..7 within 8-row group
    const int scol = (lane & 7) * 8;      // element col 0..56

    f32x4 acc0[4][4], acc1[4][4];
    const f32x4 fzero = {0.f, 0.f, 0.f, 0.f};
    #pragma unroll
    for (int i = 0; i < 4; ++i)
        #pragma unroll
        for (int j = 0; j < 4; ++j) { acc0[i][j] = fzero; acc1[i][j] = fzero; }

    for (int kt = 0; kt < 16; ++kt) {
        __syncthreads();   // previous tile's LDS reads done
        #pragma unroll
        for (int i = 0; i < 4; ++i) {
            const int r = w * 32 + i * 8 + srow;
            gload_lds16(&X[(size_t)(m0 + r) * HID_ + kt * 64 + scol],
                        &As[w * 2048 + i * 512]);
            gload_lds16(&W0[(size_t)(n0 + r) * HID_ + kt * 64 + scol],
                        &Bs0[w * 2048 + i * 512]);
            if (z == 1)
                gload_lds16(&W1[(size_t)(n0 + r) * HID_ + kt * 64 + scol],
                            &Bs1[w * 2048 + i * 512]);
        }
        __syncthreads();   // vmcnt(0) drained by compiler before barrier

        #pragma unroll
        for (int s = 0; s < 2; ++s) {
            bf16x8 a[4], b0[4];
            #pragma unroll
            for (int i = 0; i < 4; ++i) {
                a[i]  = *(const bf16x8*)&As[(wm * 64 + i * 16 + lo) * 64 + s * 32 + hi * 8];
                b0[i] = *(const bf16x8*)&Bs0[(wn * 64 + i * 16 + lo) * 64 + s * 32 + hi * 8];
            }
            #pragma unroll
            for (int i = 0; i < 4; ++i)
                #pragma unroll
                for (int j = 0; j < 4; ++j)
                    acc0[i][j] = __builtin_amdgcn_mfma_f32_16x16x32_bf16(a[i], b0[j], acc0[i][j], 0, 0, 0);
            if (z == 1) {
                bf16x8 b1[4];
                #pragma unroll
                for (int i = 0; i < 4; ++i)
                    b1[i] = *(const bf16x8*)&Bs1[(wn * 64 + i * 16 + lo) * 64 + s * 32 + hi * 8];
                #pragma unroll
                for (int i = 0; i < 4; ++i)
                    #pragma unroll
                    for (int j = 0; j < 4; ++j)
                        acc1[i][j] = __builtin_amdgcn_mfma_f32_16x16x32_bf16(a[i], b1[j], acc1[i][j], 0, 0, 0);
            }
        }
    }

    // --- epilogue 1: direct store (Q scaled, or K) from acc0
    {
        const float sc = (z == 0) ? 0.18033688011112042f : 1.0f;
        const float* bias = (z == 0) ? bq : bk;
        unsigned short* out = (z == 0) ? Qo : Ko;
        #pragma unroll
        for (int i = 0; i < 4; ++i) {
            #pragma unroll
            for (int j = 0; j < 4; ++j) {
                int col = n0 + wn * 64 + j * 16 + lo;
                float bb = bias[col];
                #pragma unroll
                for (int r = 0; r < 4; ++r) {
                    int row = m0 + wm * 64 + i * 16 + hi * 4 + r;
                    out[(size_t)row * HID_ + col] = f2bf((acc0[i][j][r] + bb) * sc);
                }
            }
        }
    }

    // --- epilogue 2 (z==1): V transpose via LDS from acc1
    if (z == 1) {
        __syncthreads();
        unsigned short* Ts = SM;   // [128][132] pitch, aliases As/Bs0/Bs1
        #pragma unroll
        for (int i = 0; i < 4; ++i) {
            #pragma unroll
            for (int j = 0; j < 4; ++j) {
                int nl = wn * 64 + j * 16 + lo;
                float bb = bv[n0 + nl];
                int ml = wm * 64 + i * 16 + hi * 4;
                ushort4 pk;
                pk.x = f2bf(acc1[i][j][0] + bb);
                pk.y = f2bf(acc1[i][j][1] + bb);
                pk.z = f2bf(acc1[i][j][2] + bb);
                pk.w = f2bf(acc1[i][j][3] + bb);
                *(ushort4*)&Ts[nl * 132 + ml] = pk;
            }
        }
        __syncthreads();
        const int nn = t >> 1;
        const int mh = (t & 1) * 64;
        const int bI = m0 >> 11;
        const int sb = (m0 & 2047) + mh;
        size_t obase = (size_t)bI * ((size_t)HID_ * S_) + (size_t)(n0 + nn) * S_ + sb;
        #pragma unroll
        for (int kk = 0; kk < 8; ++kk)
            *(uint4*)&Vo[obase + kk * 8] = *(const uint4*)&Ts[nn * 132 + mh + kk * 8];
    }
}

// ---------------------------------------------------------------------------
// Flash attention (REVERTED to round 7): swapped-QK, static max (M=0),
// deferred l-reduction, in-register P via cvt_pk + permlane swaps,
// 4 waves x 32 q = 128 q/block, KVBLK=128, double-buffered K/V.
// ---------------------------------------------------------------------------
__global__ __launch_bounds__(256) void attn_fwd(
    const unsigned short* __restrict__ Q, const unsigned short* __restrict__ K,
    const unsigned short* __restrict__ Vt, float* __restrict__ out)
{
    __shared__ __align__(16) unsigned short Ks[2][128 * 72];   // [k][d]
    __shared__ __align__(16) unsigned short Vs[2][64 * 136];   // [d][k]

    const int t = threadIdx.x;
    const int lane = t & 63;
    const int w = t >> 6;
    const int lo = lane & 15, hi = lane >> 4;

    const int id = blockIdx.x + 16 * blockIdx.y;
    const int vb = (id & 7) * 64 + (id >> 3);
    const int qt = vb & 15;
    const int bh = vb >> 4;
    const int b = bh >> 4, h = bh & 15;

    const int q0 = qt * 128;
    const size_t baseQK = (size_t)b * S_ * HID_ + (size_t)h * HD_;
    const size_t baseV  = (size_t)b * ((size_t)HID_ * S_) + (size_t)h * ((size_t)HD_ * S_);

    bf16x8 qb[2][2];
    #pragma unroll
    for (int qf = 0; qf < 2; ++qf)
        #pragma unroll
        for (int st = 0; st < 2; ++st)
            qb[qf][st] = *(const bf16x8*)&Q[baseQK + (size_t)(q0 + w * 32 + qf * 16 + lo) * HID_ + st * 32 + hi * 8];

    f32x4 O[2][4];
    const f32x4 fzero = {0.f, 0.f, 0.f, 0.f};
    f32x4 lsv[2] = {fzero, fzero};
    #pragma unroll
    for (int qf = 0; qf < 2; ++qf)
        #pragma unroll
        for (int c = 0; c < 4; ++c) O[qf][c] = fzero;

    const int krow = t >> 1, kcb = (t & 1) * 32;
    const int vrow = t >> 2, vcb = (t & 3) * 32;

    #pragma unroll
    for (int j = 0; j < 4; ++j) {
        *(uint4*)&Ks[0][krow * 72 + kcb + 8 * j] =
            *(const uint4*)&K[baseQK + (size_t)krow * HID_ + kcb + 8 * j];
        *(uint4*)&Vs[0][vrow * 136 + vcb + 8 * j] =
            *(const uint4*)&Vt[baseV + (size_t)vrow * S_ + vcb + 8 * j];
    }
    __syncthreads();

    for (int tt = 0; tt < 16; ++tt) {
        const int cur = tt & 1;
        const bool pre = (tt < 15);
        uint4 kr[4], vr[4];
        if (pre) {
            const int kn = (tt + 1) * 128;
            #pragma unroll
            for (int j = 0; j < 4; ++j) {
                kr[j] = *(const uint4*)&K[baseQK + (size_t)(kn + krow) * HID_ + kcb + 8 * j];
                vr[j] = *(const uint4*)&Vt[baseV + (size_t)vrow * S_ + kn + vcb + 8 * j];
            }
        }
        const unsigned short* Kc = Ks[cur];
        const unsigned short* Vc = Vs[cur];

        f32x4 s[2][8];
        __builtin_amdgcn_s_setprio(1);
        #pragma unroll
        for (int n = 0; n < 8; ++n) {
            bf16x8 ka0 = *(const bf16x8*)&Kc[(n * 16 + lo) * 72 + hi * 8];
            bf16x8 ka1 = *(const bf16x8*)&Kc[(n * 16 + lo) * 72 + 32 + hi * 8];
            #pragma unroll
            for (int qf = 0; qf < 2; ++qf) {
                f32x4 z = fzero;
                z = __builtin_amdgcn_mfma_f32_16x16x32_bf16(ka0, qb[qf][0], z, 0, 0, 0);
                s[qf][n] = __builtin_amdgcn_mfma_f32_16x16x32_bf16(ka1, qb[qf][1], z, 0, 0, 0);
            }
        }
        __builtin_amdgcn_s_setprio(0);

        unsigned pw[2][4][4];
        #pragma unroll
        for (int qf = 0; qf < 2; ++qf) {
            #pragma unroll
            for (int n = 0; n < 8; ++n) {
                #pragma unroll
                for (int r = 0; r < 4; ++r) s[qf][n][r] = exp2f(s[qf][n][r]);
                lsv[qf] += s[qf][n];
            }
            #pragma unroll
            for (int st = 0; st < 4; ++st) {
                #pragma unroll
                for (int p = 0; p < 2; ++p) {
                    unsigned X, Y;
                    asm("v_cvt_pk_bf16_f32 %0, %1, %2"
                        : "=v"(X) : "v"(s[qf][2 * st][2 * p]), "v"(s[qf][2 * st][2 * p + 1]));
                    asm("v_cvt_pk_bf16_f32 %0, %1, %2"
                        : "=v"(Y) : "v"(s[qf][2 * st + 1][2 * p]), "v"(s[qf][2 * st + 1][2 * p + 1]));
                    asm volatile("v_permlane32_swap_b32 %0, %1" : "+v"(X), "+v"(Y));
                    asm volatile("v_permlane16_swap_b32 %0, %1" : "+v"(X), "+v"(Y));
                    pw[qf][st][p] = X;
                    pw[qf][st][p + 2] = Y;
                }
            }
        }

        #pragma unroll
        for (int st = 0; st < 4; ++st) {
            bf16x8 pa0, pa1;
            #pragma unroll
            for (int j = 0; j < 4; ++j) {
                ((unsigned*)&pa0)[j] = pw[0][st][j];
                ((unsigned*)&pa1)[j] = pw[1][st][j];
            }
            __builtin_amdgcn_s_setprio(1);
            #pragma unroll
            for (int c = 0; c < 4; ++c) {
                bf16x8 vbf = *(const bf16x8*)&Vc[(c * 16 + lo) * 136 + st * 32 + hi * 8];
                O[0][c] = __builtin_amdgcn_mfma_f32_16x16x32_bf16(pa0, vbf, O[0][c], 0, 0, 0);
                O[1][c] = __builtin_amdgcn_mfma_f32_16x16x32_bf16(pa1, vbf, O[1][c], 0, 0, 0);
            }
            __builtin_amdgcn_s_setprio(0);
        }

        if (pre) {
            unsigned short* Kn = Ks[cur ^ 1];
            unsigned short* Vn = Vs[cur ^ 1];
            #pragma unroll
            for (int j = 0; j < 4; ++j) {
                *(uint4*)&Kn[krow * 72 + kcb + 8 * j] = kr[j];
                *(uint4*)&Vn[vrow * 136 + vcb + 8 * j] = vr[j];
            }
        }
        __syncthreads();
    }

    #pragma unroll
    for (int qf = 0; qf < 2; ++qf) {
        float l = lsv[qf][0] + lsv[qf][1] + lsv[qf][2] + lsv[qf][3];
        l += __shfl_xor(l, 16);
        l += __shfl_xor(l, 32);
        float linv[4];
        #pragma unroll
        for (int r = 0; r < 4; ++r)
            linv[r] = 1.0f / __shfl(l, (lane & 48) + hi * 4 + r);
        #pragma unroll
        for (int c = 0; c < 4; ++c) {
            #pragma unroll
            for (int r = 0; r < 4; ++r) {
                int q = q0 + w * 32 + qf * 16 + hi * 4 + r;
                out[(size_t)b * S_ * HID_ + (size_t)q * HID_ + h * HD_ + c * 16 + lo] =
                    O[qf][c][r] * linv[r];
            }
        }
    }
}

extern "C" void kernel_launch(void* const* d_in, const int* in_sizes, int n_in,
                              void* d_out, int out_size, void* d_ws, size_t ws_size,
                              hipStream_t stream) {
    const float* hs1 = (const float*)d_in[0];
    const float* hs2 = (const float*)d_in[1];
    const float* Wq  = (const float*)d_in[2];
    const float* bq  = (const float*)d_in[3];
    const float* Wk  = (const float*)d_in[4];
    const float* bk  = (const float*)d_in[5];
    const float* Wv  = (const float*)d_in[6];
    const float* bv  = (const float*)d_in[7];
    float* out = (float*)d_out;

    const size_t XY = (size_t)B_ * S_ * HID_;   // 4194304
    const size_t WW = (size_t)HID_ * HID_;      // 1048576
    unsigned short* Qb  = (unsigned short*)d_ws;
    unsigned short* Kb  = Qb + XY;
    unsigned short* Vb  = Kb + XY;              // V transposed [b][h*64+d][s]
    unsigned short* X1b = Vb + XY;
    unsigned short* X2b = X1b + XY;
    unsigned short* Wqb = X2b + XY;
    unsigned short* Wkb = Wqb + WW;
    unsigned short* Wvb = Wkb + WW;

    cvt_all<<<5632, 256, 0, stream>>>(hs1, hs2, Wq, Wk, Wv, X1b, X2b, Wqb, Wkb, Wvb);
    // z==0: Q; z==1: K+V merged (one X2 staging feeds both)
    qkv_gemm<<<dim3(32, 8, 2), 256, 0, stream>>>(X1b, X2b, Wqb, Wkb, Wvb,
                                                 bq, bk, bv, Qb, Kb, Vb);
    attn_fwd<<<dim3(16, 32), 256, 0, stream>>>(Qb, Kb, Vb, out);
}

// Round 10
// 103.097 us; speedup vs baseline: 1.7433x; 1.1230x over previous
//
#include <hip/hip_runtime.h>
#include <hip/hip_bf16.h>
#include <stdint.h>

#define B_   2
#define S_   2048
#define HID_ 1024
#define NH_  16
#define HD_  64

typedef __attribute__((ext_vector_type(4))) float f32x4;
typedef __attribute__((ext_vector_type(8))) short bf16x8;

__device__ inline unsigned short f2bf(float x) {
    __hip_bfloat16 h = __float2bfloat16(x);
    return reinterpret_cast<unsigned short&>(h);
}

__device__ inline void gload_lds16(const void* g, void* l) {
    __builtin_amdgcn_global_load_lds(
        (const __attribute__((address_space(1))) void*)g,
        (__attribute__((address_space(3))) void*)l, 16, 0, 0);
}

// ---------------------------------------------------------------------------
// Pass 0: fp32 -> bf16 conversion of X1, X2, Wq, Wk, Wv (unchanged).
// ---------------------------------------------------------------------------
__global__ __launch_bounds__(256) void cvt_all(
    const float* __restrict__ X1, const float* __restrict__ X2,
    const float* __restrict__ Wq, const float* __restrict__ Wk, const float* __restrict__ Wv,
    unsigned short* __restrict__ X1b, unsigned short* __restrict__ X2b,
    unsigned short* __restrict__ Wqb, unsigned short* __restrict__ Wkb,
    unsigned short* __restrict__ Wvb)
{
    const int id = blockIdx.x;
    const float* src;
    unsigned short* dst;
    int base;
    if (id < 2048)      { src = X1; dst = X1b; base = id; }
    else if (id < 4096) { src = X2; dst = X2b; base = id - 2048; }
    else if (id < 4608) { src = Wq; dst = Wqb; base = id - 4096; }
    else if (id < 5120) { src = Wk; dst = Wkb; base = id - 4608; }
    else                { src = Wv; dst = Wvb; base = id - 5120; }
    const size_t off = (size_t)base * 2048 + (size_t)threadIdx.x * 8;
    float4 a = *(const float4*)&src[off];
    float4 b = *(const float4*)&src[off + 4];
    unsigned short o[8] = {f2bf(a.x), f2bf(a.y), f2bf(a.z), f2bf(a.w),
                           f2bf(b.x), f2bf(b.y), f2bf(b.z), f2bf(b.w)};
    *(uint4*)&dst[off] = *(uint4*)o;
}

// ---------------------------------------------------------------------------
// QKV projection, m97 structure + T21 both-sides XOR swizzle (conflict-free
// ds_read_b128):
//  - staging: LDS dest linear (gload_lds requirement); global SOURCE column
//    pre-swizzled per lane: slot = (lane&7) ^ srow.
//  - reads: column slot = (s*4+hi) ^ (row&7) recovers the linear column.
// z==0 (Q): epilogue scaled by 0.125*log2(e), [B*S][1024] bf16
// z==1 (K): [B*S][1024] bf16
// z==2 (V): transposed to [b][h*64+d][s] bf16
// ---------------------------------------------------------------------------
__global__ __launch_bounds__(256, 3) void qkv_gemm(
    const unsigned short* __restrict__ X1b, const unsigned short* __restrict__ X2b,
    const unsigned short* __restrict__ Wqb, const unsigned short* __restrict__ Wkb,
    const unsigned short* __restrict__ Wvb,
    const float* __restrict__ bq, const float* __restrict__ bk, const float* __restrict__ bv,
    unsigned short* __restrict__ Qo, unsigned short* __restrict__ Ko, unsigned short* __restrict__ Vo)
{
    const int z = blockIdx.z;
    const unsigned short* X = (z == 0) ? X1b : X2b;
    const unsigned short* W = (z == 0) ? Wqb : (z == 1 ? Wkb : Wvb);
    const float* bias = (z == 0) ? bq : (z == 1 ? bk : bv);
    unsigned short* out = (z == 0) ? Qo : (z == 1 ? Ko : Vo);

    __shared__ __align__(16) unsigned short SM[128 * 132];
    unsigned short* As = SM;
    unsigned short* Bs = SM + 128 * 64;

    const int m0 = blockIdx.x * 128;
    const int n0 = blockIdx.y * 128;
    const int t = threadIdx.x;
    const int lane = t & 63;
    const int w = t >> 6;
    const int lo = lane & 15, hi = lane >> 4;
    const int wm = w >> 1, wn = w & 1;

    const int srow = lane >> 3;                       // 0..7 within 8-row group
    const int scol = ((lane & 7) ^ srow) * 8;         // pre-swizzled source col

    f32x4 acc[4][4];
    const f32x4 fzero = {0.f, 0.f, 0.f, 0.f};
    #pragma unroll
    for (int i = 0; i < 4; ++i)
        #pragma unroll
        for (int j = 0; j < 4; ++j) acc[i][j] = fzero;

    for (int kt = 0; kt < 16; ++kt) {
        __syncthreads();   // previous tile's LDS reads done
        #pragma unroll
        for (int i = 0; i < 4; ++i) {
            const int r = w * 32 + i * 8 + srow;
            gload_lds16(&X[(size_t)(m0 + r) * HID_ + kt * 64 + scol],
                        &As[w * 2048 + i * 512]);
            gload_lds16(&W[(size_t)(n0 + r) * HID_ + kt * 64 + scol],
                        &Bs[w * 2048 + i * 512]);
        }
        __syncthreads();   // vmcnt(0) drained by compiler before barrier

        #pragma unroll
        for (int s = 0; s < 2; ++s) {
            const int rcol = ((s * 4 + hi) ^ (lo & 7)) * 8;   // swizzled read col
            bf16x8 a[4], b[4];
            #pragma unroll
            for (int i = 0; i < 4; ++i) {
                a[i] = *(const bf16x8*)&As[(wm * 64 + i * 16 + lo) * 64 + rcol];
                b[i] = *(const bf16x8*)&Bs[(wn * 64 + i * 16 + lo) * 64 + rcol];
            }
            #pragma unroll
            for (int i = 0; i < 4; ++i)
                #pragma unroll
                for (int j = 0; j < 4; ++j)
                    acc[i][j] = __builtin_amdgcn_mfma_f32_16x16x32_bf16(a[i], b[j], acc[i][j], 0, 0, 0);
        }
    }

    if (z != 2) {
        const float sc = (z == 0) ? 0.18033688011112042f : 1.0f;
        #pragma unroll
        for (int i = 0; i < 4; ++i) {
            #pragma unroll
            for (int j = 0; j < 4; ++j) {
                int col = n0 + wn * 64 + j * 16 + lo;
                float bb = bias[col];
                #pragma unroll
                for (int r = 0; r < 4; ++r) {
                    int row = m0 + wm * 64 + i * 16 + hi * 4 + r;
                    out[(size_t)row * HID_ + col] = f2bf((acc[i][j][r] + bb) * sc);
                }
            }
        }
    } else {
        __syncthreads();
        unsigned short* Ts = SM;   // [128][132]
        #pragma unroll
        for (int i = 0; i < 4; ++i) {
            #pragma unroll
            for (int j = 0; j < 4; ++j) {
                int nl = wn * 64 + j * 16 + lo;
                float bb = bias[n0 + nl];
                int ml = wm * 64 + i * 16 + hi * 4;
                ushort4 pk;
                pk.x = f2bf(acc[i][j][0] + bb);
                pk.y = f2bf(acc[i][j][1] + bb);
                pk.z = f2bf(acc[i][j][2] + bb);
                pk.w = f2bf(acc[i][j][3] + bb);
                *(ushort4*)&Ts[nl * 132 + ml] = pk;
            }
        }
        __syncthreads();
        const int nn = t >> 1;
        const int mh = (t & 1) * 64;
        const int bI = m0 >> 11;
        const int sb = (m0 & 2047) + mh;
        size_t obase = (size_t)bI * ((size_t)HID_ * S_) + (size_t)(n0 + nn) * S_ + sb;
        #pragma unroll
        for (int kk = 0; kk < 8; ++kk)
            *(uint4*)&out[obase + kk * 8] = *(const uint4*)&Ts[nn * 132 + mh + kk * 8];
    }
}

// ---------------------------------------------------------------------------
// Flash attention: R7 structure + MFMA-computed softmax denominator.
// l[q] = sum_k P[q][k] via mfma(pa, ones, lacc) — moves 64 VALU adds/tile/wave
// to the MFMA pipe AND aligns l with O's row layout (no epilogue shuffles).
// Swapped-QK, static max (M=0), in-register P via cvt_pk + permlane.
// 4 waves x 32 q = 128 q/block, KVBLK=128, double-buffered K/V.
// ---------------------------------------------------------------------------
__global__ __launch_bounds__(256) void attn_fwd(
    const unsigned short* __restrict__ Q, const unsigned short* __restrict__ K,
    const unsigned short* __restrict__ Vt, float* __restrict__ out)
{
    __shared__ __align__(16) unsigned short Ks[2][128 * 72];   // [k][d]
    __shared__ __align__(16) unsigned short Vs[2][64 * 136];   // [d][k]

    const int t = threadIdx.x;
    const int lane = t & 63;
    const int w = t >> 6;
    const int lo = lane & 15, hi = lane >> 4;

    const int id = blockIdx.x + 16 * blockIdx.y;
    const int vb = (id & 7) * 64 + (id >> 3);
    const int qt = vb & 15;
    const int bh = vb >> 4;
    const int b = bh >> 4, h = bh & 15;

    const int q0 = qt * 128;
    const size_t baseQK = (size_t)b * S_ * HID_ + (size_t)h * HD_;
    const size_t baseV  = (size_t)b * ((size_t)HID_ * S_) + (size_t)h * ((size_t)HD_ * S_);

    bf16x8 qb[2][2];
    #pragma unroll
    for (int qf = 0; qf < 2; ++qf)
        #pragma unroll
        for (int st = 0; st < 2; ++st)
            qb[qf][st] = *(const bf16x8*)&Q[baseQK + (size_t)(q0 + w * 32 + qf * 16 + lo) * HID_ + st * 32 + hi * 8];

    f32x4 O[2][4];
    const f32x4 fzero = {0.f, 0.f, 0.f, 0.f};
    f32x4 lacc[2] = {fzero, fzero};     // MFMA-accumulated denominator
    #pragma unroll
    for (int qf = 0; qf < 2; ++qf)
        #pragma unroll
        for (int c = 0; c < 4; ++c) O[qf][c] = fzero;

    bf16x8 ones;
    #pragma unroll
    for (int j = 0; j < 4; ++j) ((unsigned*)&ones)[j] = 0x3F803F80u;

    const int krow = t >> 1, kcb = (t & 1) * 32;
    const int vrow = t >> 2, vcb = (t & 3) * 32;

    #pragma unroll
    for (int j = 0; j < 4; ++j) {
        *(uint4*)&Ks[0][krow * 72 + kcb + 8 * j] =
            *(const uint4*)&K[baseQK + (size_t)krow * HID_ + kcb + 8 * j];
        *(uint4*)&Vs[0][vrow * 136 + vcb + 8 * j] =
            *(const uint4*)&Vt[baseV + (size_t)vrow * S_ + vcb + 8 * j];
    }
    __syncthreads();

    for (int tt = 0; tt < 16; ++tt) {
        const int cur = tt & 1;
        const bool pre = (tt < 15);
        uint4 kr[4], vr[4];
        if (pre) {
            const int kn = (tt + 1) * 128;
            #pragma unroll
            for (int j = 0; j < 4; ++j) {
                kr[j] = *(const uint4*)&K[baseQK + (size_t)(kn + krow) * HID_ + kcb + 8 * j];
                vr[j] = *(const uint4*)&Vt[baseV + (size_t)vrow * S_ + kn + vcb + 8 * j];
            }
        }
        const unsigned short* Kc = Ks[cur];
        const unsigned short* Vc = Vs[cur];

        f32x4 s[2][8];
        __builtin_amdgcn_s_setprio(1);
        #pragma unroll
        for (int n = 0; n < 8; ++n) {
            bf16x8 ka0 = *(const bf16x8*)&Kc[(n * 16 + lo) * 72 + hi * 8];
            bf16x8 ka1 = *(const bf16x8*)&Kc[(n * 16 + lo) * 72 + 32 + hi * 8];
            #pragma unroll
            for (int qf = 0; qf < 2; ++qf) {
                f32x4 z = fzero;
                z = __builtin_amdgcn_mfma_f32_16x16x32_bf16(ka0, qb[qf][0], z, 0, 0, 0);
                s[qf][n] = __builtin_amdgcn_mfma_f32_16x16x32_bf16(ka1, qb[qf][1], z, 0, 0, 0);
            }
        }
        __builtin_amdgcn_s_setprio(0);

        unsigned pw[2][4][4];
        #pragma unroll
        for (int qf = 0; qf < 2; ++qf) {
            #pragma unroll
            for (int n = 0; n < 8; ++n)
                #pragma unroll
                for (int r = 0; r < 4; ++r) s[qf][n][r] = exp2f(s[qf][n][r]);
            #pragma unroll
            for (int st = 0; st < 4; ++st) {
                #pragma unroll
                for (int p = 0; p < 2; ++p) {
                    unsigned X, Y;
                    asm("v_cvt_pk_bf16_f32 %0, %1, %2"
                        : "=v"(X) : "v"(s[qf][2 * st][2 * p]), "v"(s[qf][2 * st][2 * p + 1]));
                    asm("v_cvt_pk_bf16_f32 %0, %1, %2"
                        : "=v"(Y) : "v"(s[qf][2 * st + 1][2 * p]), "v"(s[qf][2 * st + 1][2 * p + 1]));
                    asm volatile("v_permlane32_swap_b32 %0, %1" : "+v"(X), "+v"(Y));
                    asm volatile("v_permlane16_swap_b32 %0, %1" : "+v"(X), "+v"(Y));
                    pw[qf][st][p] = X;
                    pw[qf][st][p + 2] = Y;
                }
            }
        }

        #pragma unroll
        for (int st = 0; st < 4; ++st) {
            bf16x8 pa0, pa1;
            #pragma unroll
            for (int j = 0; j < 4; ++j) {
                ((unsigned*)&pa0)[j] = pw[0][st][j];
                ((unsigned*)&pa1)[j] = pw[1][st][j];
            }
            __builtin_amdgcn_s_setprio(1);
            #pragma unroll
            for (int c = 0; c < 4; ++c) {
                bf16x8 vbf = *(const bf16x8*)&Vc[(c * 16 + lo) * 136 + st * 32 + hi * 8];
                O[0][c] = __builtin_amdgcn_mfma_f32_16x16x32_bf16(pa0, vbf, O[0][c], 0, 0, 0);
                O[1][c] = __builtin_amdgcn_mfma_f32_16x16x32_bf16(pa1, vbf, O[1][c], 0, 0, 0);
            }
            // denominator: l[q] += sum_k P[q][k]  (ones-splat B operand)
            lacc[0] = __builtin_amdgcn_mfma_f32_16x16x32_bf16(pa0, ones, lacc[0], 0, 0, 0);
            lacc[1] = __builtin_amdgcn_mfma_f32_16x16x32_bf16(pa1, ones, lacc[1], 0, 0, 0);
            __builtin_amdgcn_s_setprio(0);
        }

        if (pre) {
            unsigned short* Kn = Ks[cur ^ 1];
            unsigned short* Vn = Vs[cur ^ 1];
            #pragma unroll
            for (int j = 0; j < 4; ++j) {
                *(uint4*)&Kn[krow * 72 + kcb + 8 * j] = kr[j];
                *(uint4*)&Vn[vrow * 136 + vcb + 8 * j] = vr[j];
            }
        }
        __syncthreads();
    }

    // epilogue: lacc row layout matches O rows (q = hi*4 + r) — no shuffles
    #pragma unroll
    for (int qf = 0; qf < 2; ++qf) {
        float linv[4];
        #pragma unroll
        for (int r = 0; r < 4; ++r)
            linv[r] = 1.0f / lacc[qf][r];
        #pragma unroll
        for (int c = 0; c < 4; ++c) {
            #pragma unroll
            for (int r = 0; r < 4; ++r) {
                int q = q0 + w * 32 + qf * 16 + hi * 4 + r;
                out[(size_t)b * S_ * HID_ + (size_t)q * HID_ + h * HD_ + c * 16 + lo] =
                    O[qf][c][r] * linv[r];
            }
        }
    }
}

extern "C" void kernel_launch(void* const* d_in, const int* in_sizes, int n_in,
                              void* d_out, int out_size, void* d_ws, size_t ws_size,
                              hipStream_t stream) {
    const float* hs1 = (const float*)d_in[0];
    const float* hs2 = (const float*)d_in[1];
    const float* Wq  = (const float*)d_in[2];
    const float* bq  = (const float*)d_in[3];
    const float* Wk  = (const float*)d_in[4];
    const float* bk  = (const float*)d_in[5];
    const float* Wv  = (const float*)d_in[6];
    const float* bv  = (const float*)d_in[7];
    float* out = (float*)d_out;

    const size_t XY = (size_t)B_ * S_ * HID_;   // 4194304
    const size_t WW = (size_t)HID_ * HID_;      // 1048576
    unsigned short* Qb  = (unsigned short*)d_ws;
    unsigned short* Kb  = Qb + XY;
    unsigned short* Vb  = Kb + XY;              // V transposed [b][h*64+d][s]
    unsigned short* X1b = Vb + XY;
    unsigned short* X2b = X1b + XY;
    unsigned short* Wqb = X2b + XY;
    unsigned short* Wkb = Wqb + WW;
    unsigned short* Wvb = Wkb + WW;

    cvt_all<<<5632, 256, 0, stream>>>(hs1, hs2, Wq, Wk, Wv, X1b, X2b, Wqb, Wkb, Wvb);
    qkv_gemm<<<dim3(32, 8, 3), 256, 0, stream>>>(X1b, X2b, Wqb, Wkb, Wvb,
                                                 bq, bk, bv, Qb, Kb, Vb);
    attn_fwd<<<dim3(16, 32), 256, 0, stream>>>(Qb, Kb, Vb, out);
}

// Round 11
// 103.089 us; speedup vs baseline: 1.7435x; 1.0001x over previous
//
#include <hip/hip_runtime.h>
#include <hip/hip_bf16.h>
#include <stdint.h>

#define B_   2
#define S_   2048
#define HID_ 1024
#define NH_  16
#define HD_  64

typedef __attribute__((ext_vector_type(4))) float f32x4;
typedef __attribute__((ext_vector_type(8))) short bf16x8;

__device__ inline unsigned short f2bf(float x) {
    __hip_bfloat16 h = __float2bfloat16(x);
    return reinterpret_cast<unsigned short&>(h);
}

__device__ inline void gload_lds16(const void* g, void* l) {
    __builtin_amdgcn_global_load_lds(
        (const __attribute__((address_space(1))) void*)g,
        (__attribute__((address_space(3))) void*)l, 16, 0, 0);
}

// ---------------------------------------------------------------------------
// Pass 0: fp32 -> bf16 conversion of X1, X2, Wq, Wk, Wv (unchanged).
// ---------------------------------------------------------------------------
__global__ __launch_bounds__(256) void cvt_all(
    const float* __restrict__ X1, const float* __restrict__ X2,
    const float* __restrict__ Wq, const float* __restrict__ Wk, const float* __restrict__ Wv,
    unsigned short* __restrict__ X1b, unsigned short* __restrict__ X2b,
    unsigned short* __restrict__ Wqb, unsigned short* __restrict__ Wkb,
    unsigned short* __restrict__ Wvb)
{
    const int id = blockIdx.x;
    const float* src;
    unsigned short* dst;
    int base;
    if (id < 2048)      { src = X1; dst = X1b; base = id; }
    else if (id < 4096) { src = X2; dst = X2b; base = id - 2048; }
    else if (id < 4608) { src = Wq; dst = Wqb; base = id - 4096; }
    else if (id < 5120) { src = Wk; dst = Wkb; base = id - 4608; }
    else                { src = Wv; dst = Wvb; base = id - 5120; }
    const size_t off = (size_t)base * 2048 + (size_t)threadIdx.x * 8;
    float4 a = *(const float4*)&src[off];
    float4 b = *(const float4*)&src[off + 4];
    unsigned short o[8] = {f2bf(a.x), f2bf(a.y), f2bf(a.z), f2bf(a.w),
                           f2bf(b.x), f2bf(b.y), f2bf(b.z), f2bf(b.w)};
    *(uint4*)&dst[off] = *(uint4*)o;
}

// ---------------------------------------------------------------------------
// QKV projection (unchanged from round 10): m97 structure + T21 both-sides
// XOR swizzle (conflict-free ds_read_b128).
// ---------------------------------------------------------------------------
__global__ __launch_bounds__(256, 3) void qkv_gemm(
    const unsigned short* __restrict__ X1b, const unsigned short* __restrict__ X2b,
    const unsigned short* __restrict__ Wqb, const unsigned short* __restrict__ Wkb,
    const unsigned short* __restrict__ Wvb,
    const float* __restrict__ bq, const float* __restrict__ bk, const float* __restrict__ bv,
    unsigned short* __restrict__ Qo, unsigned short* __restrict__ Ko, unsigned short* __restrict__ Vo)
{
    const int z = blockIdx.z;
    const unsigned short* X = (z == 0) ? X1b : X2b;
    const unsigned short* W = (z == 0) ? Wqb : (z == 1 ? Wkb : Wvb);
    const float* bias = (z == 0) ? bq : (z == 1 ? bk : bv);
    unsigned short* out = (z == 0) ? Qo : (z == 1 ? Ko : Vo);

    __shared__ __align__(16) unsigned short SM[128 * 132];
    unsigned short* As = SM;
    unsigned short* Bs = SM + 128 * 64;

    const int m0 = blockIdx.x * 128;
    const int n0 = blockIdx.y * 128;
    const int t = threadIdx.x;
    const int lane = t & 63;
    const int w = t >> 6;
    const int lo = lane & 15, hi = lane >> 4;
    const int wm = w >> 1, wn = w & 1;

    const int srow = lane >> 3;
    const int scol = ((lane & 7) ^ srow) * 8;

    f32x4 acc[4][4];
    const f32x4 fzero = {0.f, 0.f, 0.f, 0.f};
    #pragma unroll
    for (int i = 0; i < 4; ++i)
        #pragma unroll
        for (int j = 0; j < 4; ++j) acc[i][j] = fzero;

    for (int kt = 0; kt < 16; ++kt) {
        __syncthreads();
        #pragma unroll
        for (int i = 0; i < 4; ++i) {
            const int r = w * 32 + i * 8 + srow;
            gload_lds16(&X[(size_t)(m0 + r) * HID_ + kt * 64 + scol],
                        &As[w * 2048 + i * 512]);
            gload_lds16(&W[(size_t)(n0 + r) * HID_ + kt * 64 + scol],
                        &Bs[w * 2048 + i * 512]);
        }
        __syncthreads();

        #pragma unroll
        for (int s = 0; s < 2; ++s) {
            const int rcol = ((s * 4 + hi) ^ (lo & 7)) * 8;
            bf16x8 a[4], b[4];
            #pragma unroll
            for (int i = 0; i < 4; ++i) {
                a[i] = *(const bf16x8*)&As[(wm * 64 + i * 16 + lo) * 64 + rcol];
                b[i] = *(const bf16x8*)&Bs[(wn * 64 + i * 16 + lo) * 64 + rcol];
            }
            #pragma unroll
            for (int i = 0; i < 4; ++i)
                #pragma unroll
                for (int j = 0; j < 4; ++j)
                    acc[i][j] = __builtin_amdgcn_mfma_f32_16x16x32_bf16(a[i], b[j], acc[i][j], 0, 0, 0);
        }
    }

    if (z != 2) {
        const float sc = (z == 0) ? 0.18033688011112042f : 1.0f;
        #pragma unroll
        for (int i = 0; i < 4; ++i) {
            #pragma unroll
            for (int j = 0; j < 4; ++j) {
                int col = n0 + wn * 64 + j * 16 + lo;
                float bb = bias[col];
                #pragma unroll
                for (int r = 0; r < 4; ++r) {
                    int row = m0 + wm * 64 + i * 16 + hi * 4 + r;
                    out[(size_t)row * HID_ + col] = f2bf((acc[i][j][r] + bb) * sc);
                }
            }
        }
    } else {
        __syncthreads();
        unsigned short* Ts = SM;
        #pragma unroll
        for (int i = 0; i < 4; ++i) {
            #pragma unroll
            for (int j = 0; j < 4; ++j) {
                int nl = wn * 64 + j * 16 + lo;
                float bb = bias[n0 + nl];
                int ml = wm * 64 + i * 16 + hi * 4;
                ushort4 pk;
                pk.x = f2bf(acc[i][j][0] + bb);
                pk.y = f2bf(acc[i][j][1] + bb);
                pk.z = f2bf(acc[i][j][2] + bb);
                pk.w = f2bf(acc[i][j][3] + bb);
                *(ushort4*)&Ts[nl * 132 + ml] = pk;
            }
        }
        __syncthreads();
        const int nn = t >> 1;
        const int mh = (t & 1) * 64;
        const int bI = m0 >> 11;
        const int sb = (m0 & 2047) + mh;
        size_t obase = (size_t)bI * ((size_t)HID_ * S_) + (size_t)(n0 + nn) * S_ + sb;
        #pragma unroll
        for (int kk = 0; kk < 8; ++kk)
            *(uint4*)&out[obase + kk * 8] = *(const uint4*)&Ts[nn * 132 + mh + kk * 8];
    }
}

// ---------------------------------------------------------------------------
// Flash attention, re-tiled for occupancy: QBLK=64 (4 waves x 16 q),
// KVBLK=64 (32 tiles), grid 1024 blocks -> 4 blocks/CU, 4 waves/SIMD.
// LDS 36.9 KB. Swapped-QK, static max (M=0), MFMA denominator, in-register
// P via cvt_pk + permlane. Double-buffered K/V, 1 barrier/tile.
// ---------------------------------------------------------------------------
__global__ __launch_bounds__(256, 4) void attn_fwd(
    const unsigned short* __restrict__ Q, const unsigned short* __restrict__ K,
    const unsigned short* __restrict__ Vt, float* __restrict__ out)
{
    __shared__ __align__(16) unsigned short Ks[2][64 * 72];   // [k][d]
    __shared__ __align__(16) unsigned short Vs[2][64 * 72];   // [d][k]

    const int t = threadIdx.x;
    const int lane = t & 63;
    const int w = t >> 6;
    const int lo = lane & 15, hi = lane >> 4;

    // bijective XCD swizzle: 1024 blocks, 128/XCD => 4 consecutive bh per XCD
    const int id = blockIdx.x + 32 * blockIdx.y;
    const int vb = (id & 7) * 128 + (id >> 3);
    const int qt = vb & 31;
    const int bh = vb >> 5;
    const int b = bh >> 4, h = bh & 15;

    const int q0 = qt * 64;
    const size_t baseQK = (size_t)b * S_ * HID_ + (size_t)h * HD_;
    const size_t baseV  = (size_t)b * ((size_t)HID_ * S_) + (size_t)h * ((size_t)HD_ * S_);

    // Q B-fragments (1 q-frag of 16 rows per wave): q = q0 + w*16 + lo
    bf16x8 qb[2];
    #pragma unroll
    for (int st = 0; st < 2; ++st)
        qb[st] = *(const bf16x8*)&Q[baseQK + (size_t)(q0 + w * 16 + lo) * HID_ + st * 32 + hi * 8];

    f32x4 O[4];
    const f32x4 fzero = {0.f, 0.f, 0.f, 0.f};
    f32x4 lacc = fzero;
    #pragma unroll
    for (int c = 0; c < 4; ++c) O[c] = fzero;

    bf16x8 ones;
    #pragma unroll
    for (int j = 0; j < 4; ++j) ((unsigned*)&ones)[j] = 0x3F803F80u;

    // staging: 64 rows x 64 cols; 4 threads/row, 2 uint4 each
    const int srow = t >> 2, sc = (t & 3) * 16;

    // prologue: stage tile 0 into buf 0
    #pragma unroll
    for (int j = 0; j < 2; ++j) {
        *(uint4*)&Ks[0][srow * 72 + sc + 8 * j] =
            *(const uint4*)&K[baseQK + (size_t)srow * HID_ + sc + 8 * j];
        *(uint4*)&Vs[0][srow * 72 + sc + 8 * j] =
            *(const uint4*)&Vt[baseV + (size_t)srow * S_ + sc + 8 * j];
    }
    __syncthreads();

    for (int tt = 0; tt < 32; ++tt) {
        const int cur = tt & 1;
        const bool pre = (tt < 31);
        uint4 kr[2], vr[2];
        if (pre) {   // issue next tile's global loads early (T14)
            const int kn = (tt + 1) * 64;
            #pragma unroll
            for (int j = 0; j < 2; ++j) {
                kr[j] = *(const uint4*)&K[baseQK + (size_t)(kn + srow) * HID_ + sc + 8 * j];
                vr[j] = *(const uint4*)&Vt[baseV + (size_t)srow * S_ + kn + sc + 8 * j];
            }
        }
        const unsigned short* Kc = Ks[cur];
        const unsigned short* Vc = Vs[cur];

        // --- scores: s[n][r] = S[k = n*16 + hi*4 + r][q = lo]
        f32x4 s[4];
        __builtin_amdgcn_s_setprio(1);
        #pragma unroll
        for (int n = 0; n < 4; ++n) {
            bf16x8 ka0 = *(const bf16x8*)&Kc[(n * 16 + lo) * 72 + hi * 8];
            bf16x8 ka1 = *(const bf16x8*)&Kc[(n * 16 + lo) * 72 + 32 + hi * 8];
            f32x4 z = fzero;
            z = __builtin_amdgcn_mfma_f32_16x16x32_bf16(ka0, qb[0], z, 0, 0, 0);
            s[n] = __builtin_amdgcn_mfma_f32_16x16x32_bf16(ka1, qb[1], z, 0, 0, 0);
        }
        __builtin_amdgcn_s_setprio(0);

        // --- P = exp2(s), pack to bf16, permlane to A-frag layout
        #pragma unroll
        for (int n = 0; n < 4; ++n)
            #pragma unroll
            for (int r = 0; r < 4; ++r) s[n][r] = exp2f(s[n][r]);

        unsigned pw0[4], pw1[4];
        #pragma unroll
        for (int p = 0; p < 2; ++p) {
            unsigned X, Y;
            asm("v_cvt_pk_bf16_f32 %0, %1, %2"
                : "=v"(X) : "v"(s[0][2 * p]), "v"(s[0][2 * p + 1]));
            asm("v_cvt_pk_bf16_f32 %0, %1, %2"
                : "=v"(Y) : "v"(s[1][2 * p]), "v"(s[1][2 * p + 1]));
            asm volatile("v_permlane32_swap_b32 %0, %1" : "+v"(X), "+v"(Y));
            asm volatile("v_permlane16_swap_b32 %0, %1" : "+v"(X), "+v"(Y));
            pw0[p] = X;
            pw0[p + 2] = Y;
        }
        #pragma unroll
        for (int p = 0; p < 2; ++p) {
            unsigned X, Y;
            asm("v_cvt_pk_bf16_f32 %0, %1, %2"
                : "=v"(X) : "v"(s[2][2 * p]), "v"(s[2][2 * p + 1]));
            asm("v_cvt_pk_bf16_f32 %0, %1, %2"
                : "=v"(Y) : "v"(s[3][2 * p]), "v"(s[3][2 * p + 1]));
            asm volatile("v_permlane32_swap_b32 %0, %1" : "+v"(X), "+v"(Y));
            asm volatile("v_permlane16_swap_b32 %0, %1" : "+v"(X), "+v"(Y));
            pw1[p] = X;
            pw1[p + 2] = Y;
        }
        bf16x8 pa0, pa1;
        #pragma unroll
        for (int j = 0; j < 4; ++j) {
            ((unsigned*)&pa0)[j] = pw0[j];
            ((unsigned*)&pa1)[j] = pw1[j];
        }

        // --- O += P V; l += P*1 (MFMA denominator)
        __builtin_amdgcn_s_setprio(1);
        #pragma unroll
        for (int c = 0; c < 4; ++c) {
            bf16x8 vb0 = *(const bf16x8*)&Vc[(c * 16 + lo) * 72 + hi * 8];
            bf16x8 vb1 = *(const bf16x8*)&Vc[(c * 16 + lo) * 72 + 32 + hi * 8];
            O[c] = __builtin_amdgcn_mfma_f32_16x16x32_bf16(pa0, vb0, O[c], 0, 0, 0);
            O[c] = __builtin_amdgcn_mfma_f32_16x16x32_bf16(pa1, vb1, O[c], 0, 0, 0);
        }
        lacc = __builtin_amdgcn_mfma_f32_16x16x32_bf16(pa0, ones, lacc, 0, 0, 0);
        lacc = __builtin_amdgcn_mfma_f32_16x16x32_bf16(pa1, ones, lacc, 0, 0, 0);
        __builtin_amdgcn_s_setprio(0);

        if (pre) {   // write next tile into the other buffer
            unsigned short* Kn = Ks[cur ^ 1];
            unsigned short* Vn = Vs[cur ^ 1];
            #pragma unroll
            for (int j = 0; j < 2; ++j) {
                *(uint4*)&Kn[srow * 72 + sc + 8 * j] = kr[j];
                *(uint4*)&Vn[srow * 72 + sc + 8 * j] = vr[j];
            }
        }
        __syncthreads();
    }

    // epilogue: lacc rows match O rows (q = hi*4 + r) — no shuffles
    float linv[4];
    #pragma unroll
    for (int r = 0; r < 4; ++r) linv[r] = 1.0f / lacc[r];
    #pragma unroll
    for (int c = 0; c < 4; ++c) {
        #pragma unroll
        for (int r = 0; r < 4; ++r) {
            int q = q0 + w * 16 + hi * 4 + r;
            out[(size_t)b * S_ * HID_ + (size_t)q * HID_ + h * HD_ + c * 16 + lo] =
                O[c][r] * linv[r];
        }
    }
}

extern "C" void kernel_launch(void* const* d_in, const int* in_sizes, int n_in,
                              void* d_out, int out_size, void* d_ws, size_t ws_size,
                              hipStream_t stream) {
    const float* hs1 = (const float*)d_in[0];
    const float* hs2 = (const float*)d_in[1];
    const float* Wq  = (const float*)d_in[2];
    const float* bq  = (const float*)d_in[3];
    const float* Wk  = (const float*)d_in[4];
    const float* bk  = (const float*)d_in[5];
    const float* Wv  = (const float*)d_in[6];
    const float* bv  = (const float*)d_in[7];
    float* out = (float*)d_out;

    const size_t XY = (size_t)B_ * S_ * HID_;   // 4194304
    const size_t WW = (size_t)HID_ * HID_;      // 1048576
    unsigned short* Qb  = (unsigned short*)d_ws;
    unsigned short* Kb  = Qb + XY;
    unsigned short* Vb  = Kb + XY;              // V transposed [b][h*64+d][s]
    unsigned short* X1b = Vb + XY;
    unsigned short* X2b = X1b + XY;
    unsigned short* Wqb = X2b + XY;
    unsigned short* Wkb = Wqb + WW;
    unsigned short* Wvb = Wkb + WW;

    cvt_all<<<5632, 256, 0, stream>>>(hs1, hs2, Wq, Wk, Wv, X1b, X2b, Wqb, Wkb, Wvb);
    qkv_gemm<<<dim3(32, 8, 3), 256, 0, stream>>>(X1b, X2b, Wqb, Wkb, Wvb,
                                                 bq, bk, bv, Qb, Kb, Vb);
    attn_fwd<<<dim3(32, 32), 256, 0, stream>>>(Qb, Kb, Vb, out);
}

// Round 12
// 88.770 us; speedup vs baseline: 2.0247x; 1.1613x over previous
//
#include <hip/hip_runtime.h>
#include <hip/hip_bf16.h>
#include <stdint.h>

#define B_   2
#define S_   2048
#define HID_ 1024
#define NH_  16
#define HD_  64

typedef __attribute__((ext_vector_type(4))) float f32x4;
typedef __attribute__((ext_vector_type(8))) short bf16x8;

__device__ inline unsigned short f2bf(float x) {
    __hip_bfloat16 h = __float2bfloat16(x);
    return reinterpret_cast<unsigned short&>(h);
}

__device__ inline void gload_lds16(const void* g, void* l) {
    __builtin_amdgcn_global_load_lds(
        (const __attribute__((address_space(1))) void*)g,
        (__attribute__((address_space(3))) void*)l, 16, 0, 0);
}

__device__ inline float fast_exp2(float x) {
    float r;
    asm("v_exp_f32 %0, %1" : "=v"(r) : "v"(x));
    return r;
}

// ---------------------------------------------------------------------------
// Pass 0: fp32 -> bf16 conversion of X1, X2, Wq, Wk, Wv (unchanged).
// ---------------------------------------------------------------------------
__global__ __launch_bounds__(256) void cvt_all(
    const float* __restrict__ X1, const float* __restrict__ X2,
    const float* __restrict__ Wq, const float* __restrict__ Wk, const float* __restrict__ Wv,
    unsigned short* __restrict__ X1b, unsigned short* __restrict__ X2b,
    unsigned short* __restrict__ Wqb, unsigned short* __restrict__ Wkb,
    unsigned short* __restrict__ Wvb)
{
    const int id = blockIdx.x;
    const float* src;
    unsigned short* dst;
    int base;
    if (id < 2048)      { src = X1; dst = X1b; base = id; }
    else if (id < 4096) { src = X2; dst = X2b; base = id - 2048; }
    else if (id < 4608) { src = Wq; dst = Wqb; base = id - 4096; }
    else if (id < 5120) { src = Wk; dst = Wkb; base = id - 4608; }
    else                { src = Wv; dst = Wvb; base = id - 5120; }
    const size_t off = (size_t)base * 2048 + (size_t)threadIdx.x * 8;
    float4 a = *(const float4*)&src[off];
    float4 b = *(const float4*)&src[off + 4];
    unsigned short o[8] = {f2bf(a.x), f2bf(a.y), f2bf(a.z), f2bf(a.w),
                           f2bf(b.x), f2bf(b.y), f2bf(b.z), f2bf(b.w)};
    *(uint4*)&dst[off] = *(uint4*)o;
}

// ---------------------------------------------------------------------------
// QKV projection (unchanged from round 10): m97 structure + T21 both-sides
// XOR swizzle (conflict-free ds_read_b128).
// ---------------------------------------------------------------------------
__global__ __launch_bounds__(256, 3) void qkv_gemm(
    const unsigned short* __restrict__ X1b, const unsigned short* __restrict__ X2b,
    const unsigned short* __restrict__ Wqb, const unsigned short* __restrict__ Wkb,
    const unsigned short* __restrict__ Wvb,
    const float* __restrict__ bq, const float* __restrict__ bk, const float* __restrict__ bv,
    unsigned short* __restrict__ Qo, unsigned short* __restrict__ Ko, unsigned short* __restrict__ Vo)
{
    const int z = blockIdx.z;
    const unsigned short* X = (z == 0) ? X1b : X2b;
    const unsigned short* W = (z == 0) ? Wqb : (z == 1 ? Wkb : Wvb);
    const float* bias = (z == 0) ? bq : (z == 1 ? bk : bv);
    unsigned short* out = (z == 0) ? Qo : (z == 1 ? Ko : Vo);

    __shared__ __align__(16) unsigned short SM[128 * 132];
    unsigned short* As = SM;
    unsigned short* Bs = SM + 128 * 64;

    const int m0 = blockIdx.x * 128;
    const int n0 = blockIdx.y * 128;
    const int t = threadIdx.x;
    const int lane = t & 63;
    const int w = t >> 6;
    const int lo = lane & 15, hi = lane >> 4;
    const int wm = w >> 1, wn = w & 1;

    const int srow = lane >> 3;
    const int scol = ((lane & 7) ^ srow) * 8;

    f32x4 acc[4][4];
    const f32x4 fzero = {0.f, 0.f, 0.f, 0.f};
    #pragma unroll
    for (int i = 0; i < 4; ++i)
        #pragma unroll
        for (int j = 0; j < 4; ++j) acc[i][j] = fzero;

    for (int kt = 0; kt < 16; ++kt) {
        __syncthreads();
        #pragma unroll
        for (int i = 0; i < 4; ++i) {
            const int r = w * 32 + i * 8 + srow;
            gload_lds16(&X[(size_t)(m0 + r) * HID_ + kt * 64 + scol],
                        &As[w * 2048 + i * 512]);
            gload_lds16(&W[(size_t)(n0 + r) * HID_ + kt * 64 + scol],
                        &Bs[w * 2048 + i * 512]);
        }
        __syncthreads();

        #pragma unroll
        for (int s = 0; s < 2; ++s) {
            const int rcol = ((s * 4 + hi) ^ (lo & 7)) * 8;
            bf16x8 a[4], b[4];
            #pragma unroll
            for (int i = 0; i < 4; ++i) {
                a[i] = *(const bf16x8*)&As[(wm * 64 + i * 16 + lo) * 64 + rcol];
                b[i] = *(const bf16x8*)&Bs[(wn * 64 + i * 16 + lo) * 64 + rcol];
            }
            #pragma unroll
            for (int i = 0; i < 4; ++i)
                #pragma unroll
                for (int j = 0; j < 4; ++j)
                    acc[i][j] = __builtin_amdgcn_mfma_f32_16x16x32_bf16(a[i], b[j], acc[i][j], 0, 0, 0);
        }
    }

    if (z != 2) {
        const float sc = (z == 0) ? 0.18033688011112042f : 1.0f;
        #pragma unroll
        for (int i = 0; i < 4; ++i) {
            #pragma unroll
            for (int j = 0; j < 4; ++j) {
                int col = n0 + wn * 64 + j * 16 + lo;
                float bb = bias[col];
                #pragma unroll
                for (int r = 0; r < 4; ++r) {
                    int row = m0 + wm * 64 + i * 16 + hi * 4 + r;
                    out[(size_t)row * HID_ + col] = f2bf((acc[i][j][r] + bb) * sc);
                }
            }
        }
    } else {
        __syncthreads();
        unsigned short* Ts = SM;
        #pragma unroll
        for (int i = 0; i < 4; ++i) {
            #pragma unroll
            for (int j = 0; j < 4; ++j) {
                int nl = wn * 64 + j * 16 + lo;
                float bb = bias[n0 + nl];
                int ml = wm * 64 + i * 16 + hi * 4;
                ushort4 pk;
                pk.x = f2bf(acc[i][j][0] + bb);
                pk.y = f2bf(acc[i][j][1] + bb);
                pk.z = f2bf(acc[i][j][2] + bb);
                pk.w = f2bf(acc[i][j][3] + bb);
                *(ushort4*)&Ts[nl * 132 + ml] = pk;
            }
        }
        __syncthreads();
        const int nn = t >> 1;
        const int mh = (t & 1) * 64;
        const int bI = m0 >> 11;
        const int sb = (m0 & 2047) + mh;
        size_t obase = (size_t)bI * ((size_t)HID_ * S_) + (size_t)(n0 + nn) * S_ + sb;
        #pragma unroll
        for (int kk = 0; kk < 8; ++kk)
            *(uint4*)&out[obase + kk * 8] = *(const uint4*)&Ts[nn * 132 + mh + kk * 8];
    }
}

// ---------------------------------------------------------------------------
// Flash attention: QBLK=64 (4 waves x 16 q), KVBLK=64, grid 1024 blocks,
// 4 blocks/CU. K/V staged via global_load_lds DMA with T21 source-swizzle
// (linear [64][64] LDS, swizzled read col) — no reg staging, no ds_writes,
// conflict-free. Inline v_exp_f32 softmax (static max M=0), MFMA
// denominator, in-register P via cvt_pk + permlane. Double-buffered.
// ---------------------------------------------------------------------------
__global__ __launch_bounds__(256, 4) void attn_fwd(
    const unsigned short* __restrict__ Q, const unsigned short* __restrict__ K,
    const unsigned short* __restrict__ Vt, float* __restrict__ out)
{
    __shared__ __align__(16) unsigned short Ks[2][64 * 64];   // [k][d] swizzled
    __shared__ __align__(16) unsigned short Vs[2][64 * 64];   // [d][k] swizzled

    const int t = threadIdx.x;
    const int lane = t & 63;
    const int w = t >> 6;
    const int lo = lane & 15, hi = lane >> 4;

    // bijective XCD swizzle: 1024 blocks, 128/XCD => 4 consecutive bh per XCD
    const int id = blockIdx.x + 32 * blockIdx.y;
    const int vb = (id & 7) * 128 + (id >> 3);
    const int qt = vb & 31;
    const int bh = vb >> 5;
    const int b = bh >> 4, h = bh & 15;

    const int q0 = qt * 64;
    const size_t baseQK = (size_t)b * S_ * HID_ + (size_t)h * HD_;
    const size_t baseV  = (size_t)b * ((size_t)HID_ * S_) + (size_t)h * ((size_t)HD_ * S_);

    // Q B-fragments (16 q-rows per wave): q = q0 + w*16 + lo
    bf16x8 qb[2];
    #pragma unroll
    for (int st = 0; st < 2; ++st)
        qb[st] = *(const bf16x8*)&Q[baseQK + (size_t)(q0 + w * 16 + lo) * HID_ + st * 32 + hi * 8];

    f32x4 O[4];
    const f32x4 fzero = {0.f, 0.f, 0.f, 0.f};
    f32x4 lacc = fzero;
    #pragma unroll
    for (int c = 0; c < 4; ++c) O[c] = fzero;

    bf16x8 ones;
    #pragma unroll
    for (int j = 0; j < 4; ++j) ((unsigned*)&ones)[j] = 0x3F803F80u;

    // DMA staging: wave w covers rows w*16..w*16+15 (2 chunks of 8 rows).
    // Source col pre-swizzled so LDS content is column-swizzled (T21).
    const int srow = lane >> 3;                    // 0..7 within chunk
    const int scol = ((lane & 7) ^ srow) * 8;      // swizzled source col

    auto STAGE = [&](int buf, int kn) {
        #pragma unroll
        for (int i = 0; i < 2; ++i) {
            const int rr = w * 16 + i * 8 + srow;
            gload_lds16(&K[baseQK + (size_t)(kn + rr) * HID_ + scol],
                        &Ks[buf][w * 1024 + i * 512]);
            gload_lds16(&Vt[baseV + (size_t)rr * S_ + kn + scol],
                        &Vs[buf][w * 1024 + i * 512]);
        }
    };

    // prologue: stage tile 0
    STAGE(0, 0);
    __syncthreads();

    for (int tt = 0; tt < 32; ++tt) {
        const int cur = tt & 1;
        if (tt < 31) STAGE(cur ^ 1, (tt + 1) * 64);   // DMA next tile (T14)

        const unsigned short* Kc = Ks[cur];
        const unsigned short* Vc = Vs[cur];

        // --- scores: s[n][r] = S[k = n*16 + hi*4 + r][q = lo]
        f32x4 s[4];
        __builtin_amdgcn_s_setprio(1);
        #pragma unroll
        for (int n = 0; n < 4; ++n) {
            const int rc0 = (hi ^ (lo & 7)) * 8;
            const int rc1 = ((4 + hi) ^ (lo & 7)) * 8;
            bf16x8 ka0 = *(const bf16x8*)&Kc[(n * 16 + lo) * 64 + rc0];
            bf16x8 ka1 = *(const bf16x8*)&Kc[(n * 16 + lo) * 64 + rc1];
            f32x4 z = fzero;
            z = __builtin_amdgcn_mfma_f32_16x16x32_bf16(ka0, qb[0], z, 0, 0, 0);
            s[n] = __builtin_amdgcn_mfma_f32_16x16x32_bf16(ka1, qb[1], z, 0, 0, 0);
        }
        __builtin_amdgcn_s_setprio(0);

        // --- P = exp2(s) (static max), single-instruction v_exp_f32
        #pragma unroll
        for (int n = 0; n < 4; ++n)
            #pragma unroll
            for (int r = 0; r < 4; ++r) {
                float v = s[n][r];
                s[n][r] = fast_exp2(v);
            }

        // pack to bf16 + permlane to PV A-frag layout
        unsigned pw0[4], pw1[4];
        #pragma unroll
        for (int p = 0; p < 2; ++p) {
            unsigned X, Y;
            asm("v_cvt_pk_bf16_f32 %0, %1, %2"
                : "=v"(X) : "v"(s[0][2 * p]), "v"(s[0][2 * p + 1]));
            asm("v_cvt_pk_bf16_f32 %0, %1, %2"
                : "=v"(Y) : "v"(s[1][2 * p]), "v"(s[1][2 * p + 1]));
            asm volatile("v_permlane32_swap_b32 %0, %1" : "+v"(X), "+v"(Y));
            asm volatile("v_permlane16_swap_b32 %0, %1" : "+v"(X), "+v"(Y));
            pw0[p] = X;
            pw0[p + 2] = Y;
        }
        #pragma unroll
        for (int p = 0; p < 2; ++p) {
            unsigned X, Y;
            asm("v_cvt_pk_bf16_f32 %0, %1, %2"
                : "=v"(X) : "v"(s[2][2 * p]), "v"(s[2][2 * p + 1]));
            asm("v_cvt_pk_bf16_f32 %0, %1, %2"
                : "=v"(Y) : "v"(s[3][2 * p]), "v"(s[3][2 * p + 1]));
            asm volatile("v_permlane32_swap_b32 %0, %1" : "+v"(X), "+v"(Y));
            asm volatile("v_permlane16_swap_b32 %0, %1" : "+v"(X), "+v"(Y));
            pw1[p] = X;
            pw1[p + 2] = Y;
        }
        bf16x8 pa0, pa1;
        #pragma unroll
        for (int j = 0; j < 4; ++j) {
            ((unsigned*)&pa0)[j] = pw0[j];
            ((unsigned*)&pa1)[j] = pw1[j];
        }

        // --- O += P V; l += P*1 (MFMA denominator)
        __builtin_amdgcn_s_setprio(1);
        #pragma unroll
        for (int c = 0; c < 4; ++c) {
            const int rc0 = (hi ^ (lo & 7)) * 8;
            const int rc1 = ((4 + hi) ^ (lo & 7)) * 8;
            bf16x8 vb0 = *(const bf16x8*)&Vc[(c * 16 + lo) * 64 + rc0];
            bf16x8 vb1 = *(const bf16x8*)&Vc[(c * 16 + lo) * 64 + rc1];
            O[c] = __builtin_amdgcn_mfma_f32_16x16x32_bf16(pa0, vb0, O[c], 0, 0, 0);
            O[c] = __builtin_amdgcn_mfma_f32_16x16x32_bf16(pa1, vb1, O[c], 0, 0, 0);
        }
        lacc = __builtin_amdgcn_mfma_f32_16x16x32_bf16(pa0, ones, lacc, 0, 0, 0);
        lacc = __builtin_amdgcn_mfma_f32_16x16x32_bf16(pa1, ones, lacc, 0, 0, 0);
        __builtin_amdgcn_s_setprio(0);

        __syncthreads();   // drains DMA (vmcnt) + orders buffer reuse
    }

    // epilogue: lacc rows match O rows (q = hi*4 + r) — no shuffles
    float linv[4];
    #pragma unroll
    for (int r = 0; r < 4; ++r) linv[r] = 1.0f / lacc[r];
    #pragma unroll
    for (int c = 0; c < 4; ++c) {
        #pragma unroll
        for (int r = 0; r < 4; ++r) {
            int q = q0 + w * 16 + hi * 4 + r;
            out[(size_t)b * S_ * HID_ + (size_t)q * HID_ + h * HD_ + c * 16 + lo] =
                O[c][r] * linv[r];
        }
    }
}

extern "C" void kernel_launch(void* const* d_in, const int* in_sizes, int n_in,
                              void* d_out, int out_size, void* d_ws, size_t ws_size,
                              hipStream_t stream) {
    const float* hs1 = (const float*)d_in[0];
    const float* hs2 = (const float*)d_in[1];
    const float* Wq  = (const float*)d_in[2];
    const float* bq  = (const float*)d_in[3];
    const float* Wk  = (const float*)d_in[4];
    const float* bk  = (const float*)d_in[5];
    const float* Wv  = (const float*)d_in[6];
    const float* bv  = (const float*)d_in[7];
    float* out = (float*)d_out;

    const size_t XY = (size_t)B_ * S_ * HID_;   // 4194304
    const size_t WW = (size_t)HID_ * HID_;      // 1048576
    unsigned short* Qb  = (unsigned short*)d_ws;
    unsigned short* Kb  = Qb + XY;
    unsigned short* Vb  = Kb + XY;              // V transposed [b][h*64+d][s]
    unsigned short* X1b = Vb + XY;
    unsigned short* X2b = X1b + XY;
    unsigned short* Wqb = X2b + XY;
    unsigned short* Wkb = Wqb + WW;
    unsigned short* Wvb = Wkb + WW;

    cvt_all<<<5632, 256, 0, stream>>>(hs1, hs2, Wq, Wk, Wv, X1b, X2b, Wqb, Wkb, Wvb);
    qkv_gemm<<<dim3(32, 8, 3), 256, 0, stream>>>(X1b, X2b, Wqb, Wkb, Wvb,
                                                 bq, bk, bv, Qb, Kb, Vb);
    attn_fwd<<<dim3(32, 32), 256, 0, stream>>>(Qb, Kb, Vb, out);
}